// Round 1
// baseline (346.026 us; speedup 1.0000x reference)
//
#include <hip/hip_runtime.h>
#include <cmath>

#define D_ 128
#define H_ 256
#define W4 64                         // 4-elem groups per row (256 wide)
#define PS (H_*W4)                    // plane stride in groups (16384)
#define NTOT (2*128*256*256)
#define GBLK 2048                     // b(2) * d(128) * h-eighth(8)
#define ROWS 8                        // rows per thread (was 16): 2x grid -> 8 blk/CU
#define STOPF 1e-4f

typedef _Float16 h4 __attribute__((ext_vector_type(4)));

__device__ __forceinline__ float lk(float x){ return x >= 0.f ? x : 0.01f*x; }
__device__ __forceinline__ float4 mn4(float4 a, float4 b){
    return make_float4(fminf(a.x,b.x),fminf(a.y,b.y),fminf(a.z,b.z),fminf(a.w,b.w)); }
__device__ __forceinline__ float4 mx4(float4 a, float4 b){
    return make_float4(fmaxf(a.x,b.x),fmaxf(a.y,b.y),fmaxf(a.z,b.z),fmaxf(a.w,b.w)); }
__device__ __forceinline__ float4 ld4(const float4* p){ return *p; }
__device__ __forceinline__ float4 ld4(const h4* p){
    h4 v = *p; return make_float4((float)v.x,(float)v.y,(float)v.z,(float)v.w); }
__device__ __forceinline__ void st4(h4* p, float4 v){
    h4 r; r.x=(_Float16)v.x; r.y=(_Float16)v.y; r.z=(_Float16)v.z; r.w=(_Float16)v.w; *p = r; }

// geometry: block bi covers (b, d, h-eighth); each wave owns ROWS rows at fixed lane.
// h-eighth lives in the LOW 3 bits of blockIdx so d-neighbor blocks (which share
// X planes) land on the same XCD under round-robin dispatch -> L2 plane reuse.
struct Geo { int lane, h0; size_t pbase; bool pm, pp; };
__device__ __forceinline__ Geo mkgeo(int tid, int bi){
    Geo g;
    g.lane = tid & 63;
    int wv = tid >> 6;
    int q = bi & 7, d = (bi >> 3) & 127, b = bi >> 10;
    g.h0 = q*32 + wv*ROWS;
    g.pbase = ((size_t)(b*128 + d))*PS + (size_t)g.lane;
    g.pm = (d > 0); g.pp = (d < 127);
    return g;
}

// Fused phase on buffer X: E = erode3(X) (the next image, written out) and
// O = dilate3(X) consumed inline. fp16 morphology is EXACT after the single
// initial rounding (min/max only select values), so no bias on the stop norm.
// MODE 0: erode only (P0). MODE 1: S = leaky(C - O) (init).
// MODE 2: update, norm=|S_new| (iter 0). MODE 3: update, norm=|update|.
// Thread: ROWS rows at fixed (b,d,lane); depth-min ring + vertical window +
// horizontal via 2 cross-lane shuffles (wave's 64 lanes == one full W row).
template<int MODE, typename XT, typename CT>
__device__ __forceinline__ double phase_core(
    const XT* __restrict__ Xm, const XT* __restrict__ Xc, const XT* __restrict__ Xp,
    bool pm, bool pp,
    h4* __restrict__ Ep, const CT* __restrict__ Cp, h4* __restrict__ Sp,
    float lr, int h0, int lane)
{
    const float INF = __builtin_inff();
    float4 dmn[3], dmx[3];
    double loc = 0.0;
    auto ldrow = [&](int j){
        int s = j % 3; int h = h0 - 1 + j;
        if (h >= 0 && h < H_){
            float4 v = ld4(Xc + h*W4); float4 mn = v, mx = v;
            if (pm){ float4 u = ld4(Xm + h*W4); mn = mn4(mn,u); if constexpr(MODE>=1) mx = mx4(mx,u); }
            if (pp){ float4 u = ld4(Xp + h*W4); mn = mn4(mn,u); if constexpr(MODE>=1) mx = mx4(mx,u); }
            dmn[s] = mn; if constexpr(MODE>=1) dmx[s] = mx;
        } else {
            dmn[s] = make_float4(INF,INF,INF,INF);
            if constexpr(MODE>=1) dmx[s] = make_float4(-INF,-INF,-INF,-INF);
        }
    };
    ldrow(0); ldrow(1);
#pragma unroll
    for (int r = 0; r < ROWS; ++r){
        ldrow(r+2);
        float4 vmn = mn4(dmn[0], mn4(dmn[1], dmn[2]));
        float lmn = __shfl_up(vmn.w,1);   if (lane == 0)  lmn = INF;
        float rmn = __shfl_down(vmn.x,1); if (lane == 63) rmn = INF;
        float4 e;
        e.x = fminf(lmn,  fminf(vmn.x,vmn.y));
        e.y = fminf(vmn.x,fminf(vmn.y,vmn.z));
        e.z = fminf(vmn.y,fminf(vmn.z,vmn.w));
        e.w = fminf(vmn.z,fminf(vmn.w,rmn));
        st4(Ep + (h0+r)*W4, e);
        if constexpr(MODE >= 1){
            float4 vmx = mx4(dmx[0], mx4(dmx[1], dmx[2]));
            float lmx = __shfl_up(vmx.w,1);   if (lane == 0)  lmx = -INF;
            float rmx = __shfl_down(vmx.x,1); if (lane == 63) rmx = -INF;
            float4 o;
            o.x = fmaxf(lmx,  fmaxf(vmx.x,vmx.y));
            o.y = fmaxf(vmx.x,fmaxf(vmx.y,vmx.z));
            o.z = fmaxf(vmx.y,fmaxf(vmx.z,vmx.w));
            o.w = fmaxf(vmx.z,fmaxf(vmx.w,rmx));
            float4 a = ld4(Cp + (h0+r)*W4);
            if constexpr(MODE == 1){
                float4 s0;
                s0.x = lk(a.x-o.x); s0.y = lk(a.y-o.y);
                s0.z = lk(a.z-o.z); s0.w = lk(a.w-o.w);
                st4(Sp + (h0+r)*W4, s0);
            } else {
                float4 s = ld4(Sp + (h0+r)*W4);
                float4 up; float dl;
                dl = lk(a.x-o.x); up.x = lk(dl - s.x*dl)*lr; s.x += up.x;
                dl = lk(a.y-o.y); up.y = lk(dl - s.y*dl)*lr; s.y += up.y;
                dl = lk(a.z-o.z); up.z = lk(dl - s.z*dl)*lr; s.z += up.z;
                dl = lk(a.w-o.w); up.w = lk(dl - s.w*dl)*lr; s.w += up.w;
                st4(Sp + (h0+r)*W4, s);
                if constexpr(MODE == 2)
                    loc += (double)(fabsf(s.x)+fabsf(s.y)+fabsf(s.z)+fabsf(s.w));
                else
                    loc += (double)(fabsf(up.x)+fabsf(up.y)+fabsf(up.z)+fabsf(up.w));
            }
        }
    }
    return loc;
}

// P0: R0 = erode(img0)   (fp32 in, fp16 out); also zero-inits the frozen flag.
__global__ __launch_bounds__(256,8) void p0_k(const float* __restrict__ img0,
                                              h4* __restrict__ R0,
                                              int* __restrict__ frozen){
    if (blockIdx.x == 0 && threadIdx.x == 0) *frozen = 0;
    Geo g = mkgeo(threadIdx.x, blockIdx.x);
    const float4* Xc = (const float4*)img0 + g.pbase;
    phase_core<0,float4,float4>(Xc-PS, Xc, Xc+PS, g.pm, g.pp, R0+g.pbase,
                                (const float4*)nullptr, (h4*)nullptr, 0.f, g.h0, g.lane);
}

// P1: R1 = erode(R0); S = leaky(img0 - dilate(R0))
__global__ __launch_bounds__(256,8) void p1_k(const h4* __restrict__ R0,
                                              const float* __restrict__ img0,
                                              h4* __restrict__ R1,
                                              h4* __restrict__ S){
    Geo g = mkgeo(threadIdx.x, blockIdx.x);
    const h4* Xc = R0 + g.pbase;
    phase_core<1,h4,float4>(Xc-PS, Xc, Xc+PS, g.pm, g.pp, R1+g.pbase,
                            (const float4*)img0 + g.pbase, S+g.pbase, 0.f, g.h0, g.lane);
}

// Update phase i: self-gates on sticky frozen + reduce of previous partials.
// X = img_{i+2} ring slot, C = img_{i+1}, E-out = img_{i+3} (next X).
template<int MODE>   // 2 (i==0, norm=|S|) or 3 (i>0, norm=|up|)
__global__ __launch_bounds__(256,8) void upd_k(const h4* __restrict__ Xb,
                                               const h4* __restrict__ Cb,
                                               h4* __restrict__ Eb,
                                               h4* __restrict__ Sb,
                                               const double* __restrict__ pr,
                                               double* __restrict__ pw,
                                               int* __restrict__ frozen,
                                               float lr){
    if (*frozen) return;                       // cheap short-circuit after stop
    __shared__ double sm[4];
    int tid = threadIdx.x;
    int lane = tid & 63, wv = tid >> 6;
    if constexpr(MODE == 3){
        // every block reduces previous phase's GBLK partials identically
        double v = 0.0;
#pragma unroll
        for (int j = 0; j < GBLK/256; ++j) v += pr[tid + 256*j];
#pragma unroll
        for (int o = 32; o; o >>= 1) v += __shfl_down(v, o);
        if (lane == 0) sm[wv] = v;
        __syncthreads();
        double tot = sm[0] + sm[1] + sm[2] + sm[3];
        if ((float)(tot / (double)NTOT) < STOPF){
            if (tid == 0) *frozen = 1;         // benign multi-block same-value write
            return;
        }
        __syncthreads();                       // protect sm reuse below
    }
    Geo g = mkgeo(tid, blockIdx.x);
    const h4* Xc = Xb + g.pbase;
    double loc = phase_core<MODE,h4,h4>(Xc-PS, Xc, Xc+PS, g.pm, g.pp, Eb+g.pbase,
                                        Cb+g.pbase, Sb+g.pbase, lr, g.h0, g.lane);
#pragma unroll
    for (int o = 32; o; o >>= 1) loc += __shfl_down(loc, o);
    if (lane == 0) sm[wv] = loc;
    __syncthreads();
    if (tid == 0) pw[blockIdx.x] = sm[0]+sm[1]+sm[2]+sm[3];
}

// dt == 0 identically (stride-1 window contains center) -> out = 1.1 * S
__global__ __launch_bounds__(256) void scale_k(const h4* __restrict__ S,
                                               float* __restrict__ out){
    int t = blockIdx.x*256 + threadIdx.x;      // 4096 blocks * 256 thr * 4 groups
#pragma unroll
    for (int c = 0; c < 4; ++c){
        int i = t + c*1048576;
        float4 s = ld4(S + i);
        float4 r = make_float4(1.1f*s.x, 1.1f*s.y, 1.1f*s.z, 1.1f*s.w);
        *(float4*)(out + (size_t)i*4) = r;
    }
}

extern "C" void kernel_launch(void* const* d_in, const int* in_sizes, int n_in,
                              void* d_out, int out_size, void* d_ws, size_t ws_size,
                              hipStream_t stream){
    const float* img0 = (const float*)d_in[0];
    float* out = (float*)d_out;
    char* ws = (char*)d_ws;
    size_t volh = (size_t)NTOT * 2;            // fp16 volume: 33.5 MB
    h4* ring[3] = { (h4*)ws, (h4*)(ws + volh), (h4*)(ws + 2*volh) };
    h4* S       = (h4*)(ws + 3*volh);
    double* parts[2] = { (double*)(ws + 4*volh), (double*)(ws + 4*volh) + GBLK };
    int* frozen = (int*)(ws + 4*volh + 2*GBLK*sizeof(double));

    dim3 blk(256), grd(GBLK);
    // R0 = img_1 = erode(img0); R1 = img_2 = erode(R0); S = leaky(img0 - open(img0))
    hipLaunchKernelGGL(p0_k, grd, blk, 0, stream, img0, ring[0], frozen);
    hipLaunchKernelGGL(p1_k, grd, blk, 0, stream, ring[0], img0, ring[1], S);

    // iter i: C = img_{i+1} = ring[i%3], X = img_{i+2} = ring[(i+1)%3],
    //         E = img_{i+3} -> ring[(i+2)%3]
    for (int i = 0; i < 20; ++i){
        h4* C = ring[i % 3];
        h4* X = ring[(i+1) % 3];
        h4* E = ring[(i+2) % 3];
        float lr = (float)(0.1 * pow(0.5, (double)(i / 4)));
        double* pw = parts[i & 1];
        double* pr = parts[1 - (i & 1)];
        if (i == 0)
            hipLaunchKernelGGL((upd_k<2>), grd, blk, 0, stream, X, C, E, S, pr, pw, frozen, lr);
        else
            hipLaunchKernelGGL((upd_k<3>), grd, blk, 0, stream, X, C, E, S, pr, pw, frozen, lr);
    }
    hipLaunchKernelGGL(scale_k, dim3(4096), blk, 0, stream, S, out);
}

// Round 2
// 302.108 us; speedup vs baseline: 1.1454x; 1.1454x over previous
//
#include <hip/hip_runtime.h>
#include <cmath>

#define D_ 128
#define H_ 256
#define W4 64                         // 4-elem groups per row (256 wide)
#define PS (H_*W4)                    // plane stride in groups (16384)
#define NTOT (2*128*256*256)
#define GBLK 2048                     // b(2) * d(128) * h-eighth(8)
#define ROWS 8                        // rows per thread: 2048 blocks -> 8 blk/CU
#define STOPF 1e-4f

typedef _Float16 h4 __attribute__((ext_vector_type(4)));

__device__ __forceinline__ float lk(float x){ return x >= 0.f ? x : 0.01f*x; }
__device__ __forceinline__ float4 mn4(float4 a, float4 b){
    return make_float4(fminf(a.x,b.x),fminf(a.y,b.y),fminf(a.z,b.z),fminf(a.w,b.w)); }
__device__ __forceinline__ float4 mx4(float4 a, float4 b){
    return make_float4(fmaxf(a.x,b.x),fmaxf(a.y,b.y),fmaxf(a.z,b.z),fmaxf(a.w,b.w)); }
__device__ __forceinline__ float4 ld4(const float4* p){ return *p; }
__device__ __forceinline__ float4 ld4(const h4* p){
    h4 v = *p; return make_float4((float)v.x,(float)v.y,(float)v.z,(float)v.w); }
__device__ __forceinline__ void st4(h4* p, float4 v){
    h4 r; r.x=(_Float16)v.x; r.y=(_Float16)v.y; r.z=(_Float16)v.z; r.w=(_Float16)v.w; *p = r; }

// geometry: block bi covers (b, d, h-eighth); each wave owns ROWS rows at fixed lane.
// h-eighth lives in the LOW 3 bits of blockIdx so d-neighbor blocks (which share
// X planes) land on the same XCD under round-robin dispatch -> L2 plane reuse.
struct Geo { int lane, h0; size_t pbase; bool pm, pp; };
__device__ __forceinline__ Geo mkgeo(int tid, int bi){
    Geo g;
    g.lane = tid & 63;
    int wv = tid >> 6;
    int q = bi & 7, d = (bi >> 3) & 127, b = bi >> 10;
    g.h0 = q*32 + wv*ROWS;
    g.pbase = ((size_t)(b*128 + d))*PS + (size_t)g.lane;
    g.pm = (d > 0); g.pp = (d < 127);
    return g;
}

// Fused phase on buffer X: E = erode3(X) (the next image, written out) and
// O = dilate3(X) consumed inline. fp16 morphology is EXACT after the single
// initial rounding (min/max only select values), so no bias on the stop norm.
// MODE 0: erode only (P0). MODE 1: S = leaky(C - O) (init).
// MODE 2: update, norm=|S_new| (iter 0). MODE 3: update, norm=|update|.
// Thread: ROWS rows at fixed (b,d,lane); depth-min ring + vertical window +
// horizontal via 2 cross-lane shuffles (wave's 64 lanes == one full W row).
template<int MODE, typename XT, typename CT>
__device__ __forceinline__ double phase_core(
    const XT* __restrict__ Xm, const XT* __restrict__ Xc, const XT* __restrict__ Xp,
    bool pm, bool pp,
    h4* __restrict__ Ep, const CT* __restrict__ Cp, h4* __restrict__ Sp,
    float lr, int h0, int lane)
{
    const float INF = __builtin_inff();
    float4 dmn[3], dmx[3];
    double loc = 0.0;
    auto ldrow = [&](int j){
        int s = j % 3; int h = h0 - 1 + j;
        if (h >= 0 && h < H_){
            float4 v = ld4(Xc + h*W4); float4 mn = v, mx = v;
            if (pm){ float4 u = ld4(Xm + h*W4); mn = mn4(mn,u); if constexpr(MODE>=1) mx = mx4(mx,u); }
            if (pp){ float4 u = ld4(Xp + h*W4); mn = mn4(mn,u); if constexpr(MODE>=1) mx = mx4(mx,u); }
            dmn[s] = mn; if constexpr(MODE>=1) dmx[s] = mx;
        } else {
            dmn[s] = make_float4(INF,INF,INF,INF);
            if constexpr(MODE>=1) dmx[s] = make_float4(-INF,-INF,-INF,-INF);
        }
    };
    ldrow(0); ldrow(1);
#pragma unroll
    for (int r = 0; r < ROWS; ++r){
        ldrow(r+2);
        float4 vmn = mn4(dmn[0], mn4(dmn[1], dmn[2]));
        float lmn = __shfl_up(vmn.w,1);   if (lane == 0)  lmn = INF;
        float rmn = __shfl_down(vmn.x,1); if (lane == 63) rmn = INF;
        float4 e;
        e.x = fminf(lmn,  fminf(vmn.x,vmn.y));
        e.y = fminf(vmn.x,fminf(vmn.y,vmn.z));
        e.z = fminf(vmn.y,fminf(vmn.z,vmn.w));
        e.w = fminf(vmn.z,fminf(vmn.w,rmn));
        st4(Ep + (h0+r)*W4, e);
        if constexpr(MODE >= 1){
            float4 vmx = mx4(dmx[0], mx4(dmx[1], dmx[2]));
            float lmx = __shfl_up(vmx.w,1);   if (lane == 0)  lmx = -INF;
            float rmx = __shfl_down(vmx.x,1); if (lane == 63) rmx = -INF;
            float4 o;
            o.x = fmaxf(lmx,  fmaxf(vmx.x,vmx.y));
            o.y = fmaxf(vmx.x,fmaxf(vmx.y,vmx.z));
            o.z = fmaxf(vmx.y,fmaxf(vmx.z,vmx.w));
            o.w = fmaxf(vmx.z,fmaxf(vmx.w,rmx));
            float4 a = ld4(Cp + (h0+r)*W4);
            if constexpr(MODE == 1){
                float4 s0;
                s0.x = lk(a.x-o.x); s0.y = lk(a.y-o.y);
                s0.z = lk(a.z-o.z); s0.w = lk(a.w-o.w);
                st4(Sp + (h0+r)*W4, s0);
            } else {
                float4 s = ld4(Sp + (h0+r)*W4);
                float4 up; float dl;
                dl = lk(a.x-o.x); up.x = lk(dl - s.x*dl)*lr; s.x += up.x;
                dl = lk(a.y-o.y); up.y = lk(dl - s.y*dl)*lr; s.y += up.y;
                dl = lk(a.z-o.z); up.z = lk(dl - s.z*dl)*lr; s.z += up.z;
                dl = lk(a.w-o.w); up.w = lk(dl - s.w*dl)*lr; s.w += up.w;
                st4(Sp + (h0+r)*W4, s);
                if constexpr(MODE == 2)
                    loc += (double)(fabsf(s.x)+fabsf(s.y)+fabsf(s.z)+fabsf(s.w));
                else
                    loc += (double)(fabsf(up.x)+fabsf(up.y)+fabsf(up.z)+fabsf(up.w));
            }
        }
    }
    return loc;
}

// P0: R0 = erode(img0)   (fp32 in, fp16 out); also zero-inits the frozen flag.
__global__ __launch_bounds__(256) void p0_k(const float* __restrict__ img0,
                                            h4* __restrict__ R0,
                                            int* __restrict__ frozen){
    if (blockIdx.x == 0 && threadIdx.x == 0) *frozen = 0;
    Geo g = mkgeo(threadIdx.x, blockIdx.x);
    const float4* Xc = (const float4*)img0 + g.pbase;
    phase_core<0,float4,float4>(Xc-PS, Xc, Xc+PS, g.pm, g.pp, R0+g.pbase,
                                (const float4*)nullptr, (h4*)nullptr, 0.f, g.h0, g.lane);
}

// P1: R1 = erode(R0); S = leaky(img0 - dilate(R0))
__global__ __launch_bounds__(256) void p1_k(const h4* __restrict__ R0,
                                            const float* __restrict__ img0,
                                            h4* __restrict__ R1,
                                            h4* __restrict__ S){
    Geo g = mkgeo(threadIdx.x, blockIdx.x);
    const h4* Xc = R0 + g.pbase;
    phase_core<1,h4,float4>(Xc-PS, Xc, Xc+PS, g.pm, g.pp, R1+g.pbase,
                            (const float4*)img0 + g.pbase, S+g.pbase, 0.f, g.h0, g.lane);
}

// Update phase i: self-gates on sticky frozen + reduce of previous partials.
// X = img_{i+2} ring slot, C = img_{i+1}, E-out = img_{i+3} (next X).
template<int MODE>   // 2 (i==0, norm=|S|) or 3 (i>0, norm=|up|)
__global__ __launch_bounds__(256) void upd_k(const h4* __restrict__ Xb,
                                             const h4* __restrict__ Cb,
                                             h4* __restrict__ Eb,
                                             h4* __restrict__ Sb,
                                             const double* __restrict__ pr,
                                             double* __restrict__ pw,
                                             int* __restrict__ frozen,
                                             float lr){
    if (*frozen) return;                       // cheap short-circuit after stop
    __shared__ double sm[4];
    int tid = threadIdx.x;
    int lane = tid & 63, wv = tid >> 6;
    if constexpr(MODE == 3){
        // every block reduces previous phase's GBLK partials identically
        double v = 0.0;
#pragma unroll
        for (int j = 0; j < GBLK/256; ++j) v += pr[tid + 256*j];
#pragma unroll
        for (int o = 32; o; o >>= 1) v += __shfl_down(v, o);
        if (lane == 0) sm[wv] = v;
        __syncthreads();
        double tot = sm[0] + sm[1] + sm[2] + sm[3];
        if ((float)(tot / (double)NTOT) < STOPF){
            if (tid == 0) *frozen = 1;         // benign multi-block same-value write
            return;
        }
        __syncthreads();                       // protect sm reuse below
    }
    Geo g = mkgeo(tid, blockIdx.x);
    const h4* Xc = Xb + g.pbase;
    double loc = phase_core<MODE,h4,h4>(Xc-PS, Xc, Xc+PS, g.pm, g.pp, Eb+g.pbase,
                                        Cb+g.pbase, Sb+g.pbase, lr, g.h0, g.lane);
#pragma unroll
    for (int o = 32; o; o >>= 1) loc += __shfl_down(loc, o);
    if (lane == 0) sm[wv] = loc;
    __syncthreads();
    if (tid == 0) pw[blockIdx.x] = sm[0]+sm[1]+sm[2]+sm[3];
}

// dt == 0 identically (stride-1 window contains center) -> out = 1.1 * S
__global__ __launch_bounds__(256) void scale_k(const h4* __restrict__ S,
                                               float* __restrict__ out){
    int t = blockIdx.x*256 + threadIdx.x;      // 4096 blocks * 256 thr * 4 groups
#pragma unroll
    for (int c = 0; c < 4; ++c){
        int i = t + c*1048576;
        float4 s = ld4(S + i);
        float4 r = make_float4(1.1f*s.x, 1.1f*s.y, 1.1f*s.z, 1.1f*s.w);
        *(float4*)(out + (size_t)i*4) = r;
    }
}

extern "C" void kernel_launch(void* const* d_in, const int* in_sizes, int n_in,
                              void* d_out, int out_size, void* d_ws, size_t ws_size,
                              hipStream_t stream){
    const float* img0 = (const float*)d_in[0];
    float* out = (float*)d_out;
    char* ws = (char*)d_ws;
    size_t volh = (size_t)NTOT * 2;            // fp16 volume: 33.5 MB
    h4* ring[3] = { (h4*)ws, (h4*)(ws + volh), (h4*)(ws + 2*volh) };
    h4* S       = (h4*)(ws + 3*volh);
    double* parts[2] = { (double*)(ws + 4*volh), (double*)(ws + 4*volh) + GBLK };
    int* frozen = (int*)(ws + 4*volh + 2*GBLK*sizeof(double));

    dim3 blk(256), grd(GBLK);
    // R0 = img_1 = erode(img0); R1 = img_2 = erode(R0); S = leaky(img0 - open(img0))
    hipLaunchKernelGGL(p0_k, grd, blk, 0, stream, img0, ring[0], frozen);
    hipLaunchKernelGGL(p1_k, grd, blk, 0, stream, ring[0], img0, ring[1], S);

    // iter i: C = img_{i+1} = ring[i%3], X = img_{i+2} = ring[(i+1)%3],
    //         E = img_{i+3} -> ring[(i+2)%3]
    for (int i = 0; i < 20; ++i){
        h4* C = ring[i % 3];
        h4* X = ring[(i+1) % 3];
        h4* E = ring[(i+2) % 3];
        float lr = (float)(0.1 * pow(0.5, (double)(i / 4)));
        double* pw = parts[i & 1];
        double* pr = parts[1 - (i & 1)];
        if (i == 0)
            hipLaunchKernelGGL((upd_k<2>), grd, blk, 0, stream, X, C, E, S, pr, pw, frozen, lr);
        else
            hipLaunchKernelGGL((upd_k<3>), grd, blk, 0, stream, X, C, E, S, pr, pw, frozen, lr);
    }
    hipLaunchKernelGGL(scale_k, dim3(4096), blk, 0, stream, S, out);
}

// Round 4
// 292.877 us; speedup vs baseline: 1.1815x; 1.0315x over previous
//
#include <hip/hip_runtime.h>
#include <cmath>

#define D_ 128
#define H_ 256
#define W4 64                         // 4-elem groups per row (256 wide)
#define PS (H_*W4)                    // plane stride in groups (16384)
#define NTOT (2*128*256*256)
#define GBLK 2048                     // b(2) * d(128) * h-eighth(8)
#define ROWS 8                        // rows per thread
#define STOPF 1e-4f

typedef _Float16 h4 __attribute__((ext_vector_type(4)));
typedef _Float16 h2v __attribute__((ext_vector_type(2)));

__device__ __forceinline__ float lk(float x){ return x >= 0.f ? x : 0.01f*x; }
__device__ __forceinline__ float4 mn4(float4 a, float4 b){
    return make_float4(fminf(a.x,b.x),fminf(a.y,b.y),fminf(a.z,b.z),fminf(a.w,b.w)); }
__device__ __forceinline__ float4 ld4(const float4* p){ return *p; }
__device__ __forceinline__ float4 ld4(const h4* p){
    h4 v = *p; return make_float4((float)v.x,(float)v.y,(float)v.z,(float)v.w); }
__device__ __forceinline__ void st4(h4* p, float4 v){
    h4 r; r.x=(_Float16)v.x; r.y=(_Float16)v.y; r.z=(_Float16)v.z; r.w=(_Float16)v.w; *p = r; }

// ---- packed fp16 helpers: v_pk_min/max_f16 via elementwise builtins on v2f16.
// min/max are pure selections -> bit-exact vs f32 path on finite data + inf sentinels.
#define PINF 0x7C007C00u
#define NINF 0xFC00FC00u
__device__ __forceinline__ uint32_t pmin(uint32_t a, uint32_t b){
    h2v r = __builtin_elementwise_min(__builtin_bit_cast(h2v,a), __builtin_bit_cast(h2v,b));
    return __builtin_bit_cast(uint32_t, r); }
__device__ __forceinline__ uint32_t pmax(uint32_t a, uint32_t b){
    h2v r = __builtin_elementwise_max(__builtin_bit_cast(h2v,a), __builtin_bit_cast(h2v,b));
    return __builtin_bit_cast(uint32_t, r); }
__device__ __forceinline__ uint2 pmin2(uint2 a, uint2 b){
    return make_uint2(pmin(a.x,b.x), pmin(a.y,b.y)); }
__device__ __forceinline__ uint2 pmax2(uint2 a, uint2 b){
    return make_uint2(pmax(a.x,b.x), pmax(a.y,b.y)); }
__device__ __forceinline__ float4 cvt4(uint32_t w01, uint32_t w23){
    h2v a = __builtin_bit_cast(h2v, w01);
    h2v b = __builtin_bit_cast(h2v, w23);
    return make_float4((float)a.x, (float)a.y, (float)b.x, (float)b.y); }

// geometry: block bi covers (b, d, h-eighth); each wave owns ROWS rows at fixed lane.
// h-eighth in LOW 3 bits of blockIdx: d-neighbor blocks (share X planes) are 8 apart
// -> same XCD under round-robin -> L2 plane reuse.
struct Geo { int lane, h0; size_t pbase; bool pm, pp; };
__device__ __forceinline__ Geo mkgeo(int tid, int bi){
    Geo g;
    g.lane = tid & 63;
    int wv = tid >> 6;
    int q = bi & 7, d = (bi >> 3) & 127, b = bi >> 10;
    g.h0 = q*32 + wv*ROWS;
    g.pbase = ((size_t)(b*128 + d))*PS + (size_t)g.lane;
    g.pm = (d > 0); g.pp = (d < 127);
    return g;
}

// ---- f32 core, p0 only (fp32 input erode) ----
__device__ __forceinline__ void phase_f32_erode(
    const float4* __restrict__ Xm, const float4* __restrict__ Xc, const float4* __restrict__ Xp,
    bool pm, bool pp, h4* __restrict__ Ep, int h0, int lane)
{
    const float INF = __builtin_inff();
    float4 dmn[3];
    auto ldrow = [&](int j){
        int s = j % 3; int h = h0 - 1 + j;
        if (h >= 0 && h < H_){
            float4 v = ld4(Xc + h*W4); float4 mn = v;
            if (pm){ mn = mn4(mn, ld4(Xm + h*W4)); }
            if (pp){ mn = mn4(mn, ld4(Xp + h*W4)); }
            dmn[s] = mn;
        } else dmn[s] = make_float4(INF,INF,INF,INF);
    };
    ldrow(0); ldrow(1);
#pragma unroll
    for (int r = 0; r < ROWS; ++r){
        ldrow(r+2);
        float4 vmn = mn4(dmn[0], mn4(dmn[1], dmn[2]));
        float lmn = __shfl_up(vmn.w,1);   if (lane == 0)  lmn = INF;
        float rmn = __shfl_down(vmn.x,1); if (lane == 63) rmn = INF;
        float4 e;
        e.x = fminf(lmn,  fminf(vmn.x,vmn.y));
        e.y = fminf(vmn.x,fminf(vmn.y,vmn.z));
        e.z = fminf(vmn.y,fminf(vmn.z,vmn.w));
        e.w = fminf(vmn.z,fminf(vmn.w,rmn));
        st4(Ep + (h0+r)*W4, e);
    }
}

// ---- packed fp16 core (p1 + update phases) ----
// E = erode3(X) written out; O = dilate3(X) consumed inline. All morphology in
// packed fp16 (bit-exact: min/max only select). S-update math identical f32
// sequence to the round-2 passing version -> numerics unchanged.
// MODE 1: S = leaky(C - O). MODE 2: update, norm=|S_new|. MODE 3: update, norm=|up|.
// 4-slot ring: X-row load issued one iteration before consumption (latency hide);
// C/S prefetched one row ahead.
template<int MODE, typename CT>
__device__ __forceinline__ double phase_pk(
    const uint2* __restrict__ Xm, const uint2* __restrict__ Xc, const uint2* __restrict__ Xp,
    bool pm, bool pp,
    uint2* __restrict__ Ep, const CT* __restrict__ Cp, h4* __restrict__ Sp,
    float lr, int h0, int lane)
{
    uint2 rmn[4], rmx[4];
    double loc = 0.0;
    auto ldrow = [&](int j){
        int s = j & 3; int h = h0 - 1 + j;
        if (h >= 0 && h < H_){
            uint2 v = *(Xc + h*W4); uint2 mn = v, mx = v;
            if (pm){ uint2 u = *(Xm + h*W4); mn = pmin2(mn,u); mx = pmax2(mx,u); }
            if (pp){ uint2 u = *(Xp + h*W4); mn = pmin2(mn,u); mx = pmax2(mx,u); }
            rmn[s] = mn; rmx[s] = mx;
        } else {
            rmn[s] = make_uint2(PINF,PINF);
            rmx[s] = make_uint2(NINF,NINF);
        }
    };
    ldrow(0); ldrow(1); ldrow(2);
    float4 a_cur = ld4(Cp + h0*W4);
    float4 s_cur = make_float4(0,0,0,0);
    if constexpr(MODE >= 2) s_cur = ld4(Sp + h0*W4);
#pragma unroll
    for (int r = 0; r < ROWS; ++r){
        if (r + 3 <= ROWS + 1) ldrow(r+3);            // distance-2 prefetch
        float4 a_nxt = a_cur, s_nxt = s_cur;
        if (r + 1 < ROWS){
            a_nxt = ld4(Cp + (h0+r+1)*W4);
            if constexpr(MODE >= 2) s_nxt = ld4(Sp + (h0+r+1)*W4);
        }
        // ring merge (rows r-1, r, r+1 -> slots r, r+1, r+2 mod 4)
        uint2 vmn = pmin2(rmn[r&3], pmin2(rmn[(r+1)&3], rmn[(r+2)&3]));
        uint2 vmx = pmax2(rmx[r&3], pmax2(rmx[(r+1)&3], rmx[(r+2)&3]));
        // horizontal: word-shift windows + 1 shuffle per edge
        uint32_t pwn = __shfl_up(vmn.y,1);   if (lane == 0)  pwn = PINF;
        uint32_t nwn = __shfl_down(vmn.x,1); if (lane == 63) nwn = PINF;
        uint32_t l01 = (pwn  >> 16) | (vmn.x << 16);  // elems [w-1, w0]
        uint32_t l23 = (vmn.x >> 16) | (vmn.y << 16); // elems [w1, w2]
        uint32_t r23 = (vmn.y >> 16) | (nwn  << 16);  // elems [w3, w4]
        uint32_t e01 = pmin(pmin(l01, vmn.x), l23);
        uint32_t e23 = pmin(pmin(l23, vmn.y), r23);
        *(Ep + (h0+r)*W4) = make_uint2(e01, e23);
        uint32_t pwx = __shfl_up(vmx.y,1);   if (lane == 0)  pwx = NINF;
        uint32_t nwx = __shfl_down(vmx.x,1); if (lane == 63) nwx = NINF;
        uint32_t L01 = (pwx  >> 16) | (vmx.x << 16);
        uint32_t L23 = (vmx.x >> 16) | (vmx.y << 16);
        uint32_t R23 = (vmx.y >> 16) | (nwx  << 16);
        uint32_t o01 = pmax(pmax(L01, vmx.x), L23);
        uint32_t o23 = pmax(pmax(L23, vmx.y), R23);
        float4 o = cvt4(o01, o23);
        float4 a = a_cur;
        if constexpr(MODE == 1){
            float4 s0;
            s0.x = lk(a.x-o.x); s0.y = lk(a.y-o.y);
            s0.z = lk(a.z-o.z); s0.w = lk(a.w-o.w);
            st4(Sp + (h0+r)*W4, s0);
        } else {
            float4 s = s_cur;
            float4 up; float dl;
            dl = lk(a.x-o.x); up.x = lk(dl - s.x*dl)*lr; s.x += up.x;
            dl = lk(a.y-o.y); up.y = lk(dl - s.y*dl)*lr; s.y += up.y;
            dl = lk(a.z-o.z); up.z = lk(dl - s.z*dl)*lr; s.z += up.z;
            dl = lk(a.w-o.w); up.w = lk(dl - s.w*dl)*lr; s.w += up.w;
            st4(Sp + (h0+r)*W4, s);
            if constexpr(MODE == 2)
                loc += (double)(fabsf(s.x)+fabsf(s.y)+fabsf(s.z)+fabsf(s.w));
            else
                loc += (double)(fabsf(up.x)+fabsf(up.y)+fabsf(up.z)+fabsf(up.w));
        }
        a_cur = a_nxt; s_cur = s_nxt;
    }
    return loc;
}

// P0: R0 = erode(img0)   (fp32 in, fp16 out); also zero-inits the frozen flag.
__global__ __launch_bounds__(256) void p0_k(const float* __restrict__ img0,
                                            h4* __restrict__ R0,
                                            int* __restrict__ frozen){
    if (blockIdx.x == 0 && threadIdx.x == 0) *frozen = 0;
    Geo g = mkgeo(threadIdx.x, blockIdx.x);
    const float4* Xc = (const float4*)img0 + g.pbase;
    phase_f32_erode(Xc-PS, Xc, Xc+PS, g.pm, g.pp, R0+g.pbase, g.h0, g.lane);
}

// P1: R1 = erode(R0); S = leaky(img0 - dilate(R0))
__global__ __launch_bounds__(256) void p1_k(const h4* __restrict__ R0,
                                            const float* __restrict__ img0,
                                            h4* __restrict__ R1,
                                            h4* __restrict__ S){
    Geo g = mkgeo(threadIdx.x, blockIdx.x);
    const uint2* Xc = (const uint2*)R0 + g.pbase;
    phase_pk<1,float4>(Xc-PS, Xc, Xc+PS, g.pm, g.pp, (uint2*)R1 + g.pbase,
                       (const float4*)img0 + g.pbase, S + g.pbase, 0.f, g.h0, g.lane);
}

// Update phase i: self-gates on sticky frozen + reduce of previous partials.
template<int MODE>   // 2 (i==0, norm=|S|) or 3 (i>0, norm=|up|)
__global__ __launch_bounds__(256) void upd_k(const h4* __restrict__ Xb,
                                             const h4* __restrict__ Cb,
                                             h4* __restrict__ Eb,
                                             h4* __restrict__ Sb,
                                             const double* __restrict__ pr,
                                             double* __restrict__ pw,
                                             int* __restrict__ frozen,
                                             float lr){
    if (*frozen) return;                       // cheap short-circuit after stop
    __shared__ double sm[4];
    int tid = threadIdx.x;
    int lane = tid & 63, wv = tid >> 6;
    if constexpr(MODE == 3){
        // every block reduces previous phase's GBLK partials identically
        double v = 0.0;
#pragma unroll
        for (int j = 0; j < GBLK/256; ++j) v += pr[tid + 256*j];
#pragma unroll
        for (int o = 32; o; o >>= 1) v += __shfl_down(v, o);
        if (lane == 0) sm[wv] = v;
        __syncthreads();
        double tot = sm[0] + sm[1] + sm[2] + sm[3];
        if ((float)(tot / (double)NTOT) < STOPF){
            if (tid == 0) *frozen = 1;         // benign multi-block same-value write
            return;
        }
        __syncthreads();                       // protect sm reuse below
    }
    Geo g = mkgeo(tid, blockIdx.x);
    const uint2* Xc = (const uint2*)Xb + g.pbase;
    double loc = phase_pk<MODE,h4>(Xc-PS, Xc, Xc+PS, g.pm, g.pp,
                                   (uint2*)Eb + g.pbase, Cb + g.pbase, Sb + g.pbase,
                                   lr, g.h0, g.lane);
#pragma unroll
    for (int o = 32; o; o >>= 1) loc += __shfl_down(loc, o);
    if (lane == 0) sm[wv] = loc;
    __syncthreads();
    if (tid == 0) pw[blockIdx.x] = sm[0]+sm[1]+sm[2]+sm[3];
}

// dt == 0 identically (stride-1 window contains center) -> out = 1.1 * S
__global__ __launch_bounds__(256) void scale_k(const h4* __restrict__ S,
                                               float* __restrict__ out){
    int t = blockIdx.x*256 + threadIdx.x;      // 4096 blocks * 256 thr * 4 groups
#pragma unroll
    for (int c = 0; c < 4; ++c){
        int i = t + c*1048576;
        float4 s = ld4(S + i);
        float4 r = make_float4(1.1f*s.x, 1.1f*s.y, 1.1f*s.z, 1.1f*s.w);
        *(float4*)(out + (size_t)i*4) = r;
    }
}

extern "C" void kernel_launch(void* const* d_in, const int* in_sizes, int n_in,
                              void* d_out, int out_size, void* d_ws, size_t ws_size,
                              hipStream_t stream){
    const float* img0 = (const float*)d_in[0];
    float* out = (float*)d_out;
    char* ws = (char*)d_ws;
    size_t volh = (size_t)NTOT * 2;            // fp16 volume: 33.5 MB
    h4* ring[3] = { (h4*)ws, (h4*)(ws + volh), (h4*)(ws + 2*volh) };
    h4* S       = (h4*)(ws + 3*volh);
    double* parts[2] = { (double*)(ws + 4*volh), (double*)(ws + 4*volh) + GBLK };
    int* frozen = (int*)(ws + 4*volh + 2*GBLK*sizeof(double));

    dim3 blk(256), grd(GBLK);
    // R0 = img_1 = erode(img0); R1 = img_2 = erode(R0); S = leaky(img0 - open(img0))
    hipLaunchKernelGGL(p0_k, grd, blk, 0, stream, img0, ring[0], frozen);
    hipLaunchKernelGGL(p1_k, grd, blk, 0, stream, ring[0], img0, ring[1], S);

    // iter i: C = img_{i+1} = ring[i%3], X = img_{i+2} = ring[(i+1)%3],
    //         E = img_{i+3} -> ring[(i+2)%3]
    for (int i = 0; i < 20; ++i){
        h4* C = ring[i % 3];
        h4* X = ring[(i+1) % 3];
        h4* E = ring[(i+2) % 3];
        float lr = (float)(0.1 * pow(0.5, (double)(i / 4)));
        double* pw = parts[i & 1];
        double* pr = parts[1 - (i & 1)];
        if (i == 0)
            hipLaunchKernelGGL((upd_k<2>), grd, blk, 0, stream, X, C, E, S, pr, pw, frozen, lr);
        else
            hipLaunchKernelGGL((upd_k<3>), grd, blk, 0, stream, X, C, E, S, pr, pw, frozen, lr);
    }
    hipLaunchKernelGGL(scale_k, dim3(4096), blk, 0, stream, S, out);
}